// Round 2
// baseline (755.592 us; speedup 1.0000x reference)
//
#include <hip/hip_runtime.h>

constexpr int VIEWS = 360;
constexpr int IMGSZ = 512;
constexpr int BATCH = 2;

// One thread per (b, v, w). Lanes = consecutive w at same view, so the 4
// bilinear gathers of adjacent lanes walk adjacent parallel lines (L1/L2
// friendly). Inner loop over h restricted to the analytically-computed
// interval where the rotated sample point can touch the image.
__global__ __launch_bounds__(256) void fp_kernel(const float* __restrict__ x,
                                                 float* __restrict__ out) {
    int t = blockIdx.x * 256 + threadIdx.x;
    int w = t & (IMGSZ - 1);
    int bv = t >> 9;          // 9 = log2(IMGSZ)
    int v = bv % VIEWS;
    int b = bv / VIEWS;

    // angle = -pi*(v+1)/360 - pi   (double trig once per thread; loop is the cost)
    double ang = -3.14159265358979323846 * (double)(v + 1) / (double)VIEWS
                 - 3.14159265358979323846;
    float c = (float)cos(ang);
    float s = (float)sin(ang);

    const float* __restrict__ img = x + (size_t)b * IMGSZ * IMGSZ;

    // ix = c*(w+0.5-256) - s*(h+0.5-256) + 255.5 = cxw - s*hh
    // iy = s*(w+0.5-256) + c*(h+0.5-256) + 255.5 = sxw + c*hh
    float xw = (float)w + 0.5f - 256.0f;
    float cxw = fmaf(c, xw, 255.5f);
    float sxw = fmaf(s, xw, 255.5f);

    // Valid hh interval: any tap contributes only if -1 < ix < 512 and -1 < iy < 512.
    float lo = -1e30f, hi = 1e30f;
    {
        float coef = -s, base = cxw;
        if (fabsf(coef) > 1e-6f) {
            float a = (-1.0f - base) / coef;
            float bq = (512.0f - base) / coef;
            lo = fmaxf(lo, fminf(a, bq));
            hi = fminf(hi, fmaxf(a, bq));
        } else if (!(base > -1.0f && base < 512.0f)) {
            lo = 1e30f; hi = -1e30f;
        }
    }
    {
        float coef = c, base = sxw;
        if (fabsf(coef) > 1e-6f) {
            float a = (-1.0f - base) / coef;
            float bq = (512.0f - base) / coef;
            lo = fmaxf(lo, fminf(a, bq));
            hi = fminf(hi, fmaxf(a, bq));
        } else if (!(base > -1.0f && base < 512.0f)) {
            lo = 1e30f; hi = -1e30f;
        }
    }
    // hh = h - 255.5; pad interval by 1 on each side, clamp safely before int cast.
    float h0f = fminf(fmaxf(floorf(lo + 255.5f) - 1.0f, 0.0f), 512.0f);
    float h1f = fminf(fmaxf(ceilf(hi + 255.5f) + 1.0f, -1.0f), 511.0f);
    int h0 = (int)h0f;
    int h1 = (int)h1f;

    float acc = 0.0f;
    for (int h = h0; h <= h1; ++h) {
        float hh = (float)h - 255.5f;
        float ix = fmaf(-s, hh, cxw);
        float iy = fmaf(c, hh, sxw);
        float fx = floorf(ix);
        float fy = floorf(iy);
        int x0 = (int)fx;
        int y0 = (int)fy;
        float wx1 = ix - fx;
        float wy1 = iy - fy;
        float wx0 = 1.0f - wx1;
        float wy0 = 1.0f - wy1;
        bool vx0 = (unsigned)x0 < (unsigned)IMGSZ;
        bool vx1 = (unsigned)(x0 + 1) < (unsigned)IMGSZ;
        bool vy0 = (unsigned)y0 < (unsigned)IMGSZ;
        bool vy1 = (unsigned)(y0 + 1) < (unsigned)IMGSZ;
        int x0c = min(max(x0, 0), IMGSZ - 1);
        int x1c = min(max(x0 + 1, 0), IMGSZ - 1);
        int y0c = min(max(y0, 0), IMGSZ - 1);
        int y1c = min(max(y0 + 1, 0), IMGSZ - 1);
        float w00 = (vx0 && vy0) ? wx0 * wy0 : 0.0f;
        float w01 = (vx1 && vy0) ? wx1 * wy0 : 0.0f;
        float w10 = (vx0 && vy1) ? wx0 * wy1 : 0.0f;
        float w11 = (vx1 && vy1) ? wx1 * wy1 : 0.0f;
        const float* r0 = img + (size_t)y0c * IMGSZ;
        const float* r1 = img + (size_t)y1c * IMGSZ;
        acc = fmaf(r0[x0c], w00, acc);
        acc = fmaf(r0[x1c], w01, acc);
        acc = fmaf(r1[x0c], w10, acc);
        acc = fmaf(r1[x1c], w11, acc);
    }

    // sino layout: (B, 1, W, VIEWS)
    out[((size_t)(b * IMGSZ + w)) * VIEWS + v] = acc * 0.5f;
}

extern "C" void kernel_launch(void* const* d_in, const int* in_sizes, int n_in,
                              void* d_out, int out_size, void* d_ws, size_t ws_size,
                              hipStream_t stream) {
    const float* x = (const float*)d_in[0];
    float* out = (float*)d_out;
    int total = BATCH * VIEWS * IMGSZ;   // 368640 threads
    fp_kernel<<<total / 256, 256, 0, stream>>>(x, out);
}

// Round 3
// 563.013 us; speedup vs baseline: 1.3421x; 1.3421x over previous
//
#include <hip/hip_runtime.h>

constexpr int VIEWS = 360;
constexpr int IMGSZ = 512;
constexpr int BATCH = 2;
constexpr int WCHUNK = 64;   // w per block
constexpr int KH = 64;       // h per LDS chunk
constexpr int MAXB = 95;     // max bounding-box dim: 64*sqrt(2)+2 taps+2 margin
constexpr int PITCH = 97;    // odd pitch -> benign LDS bank pattern

// Block = (b, v, wc): 64 detector bins, 4 waves split the h-sum 4-way.
// Per 64-h chunk: stage the rotated square's bounding box (<=95x95) in LDS
// with coalesced row loads, then bilinear-gather from LDS (ds_read_b32 with
// immediate offsets). Sampling math identical to the validated baseline.
__global__ __launch_bounds__(256) void fp_kernel(const float* __restrict__ x,
                                                 float* __restrict__ out) {
    __shared__ float tile[MAXB * PITCH];
    __shared__ float part[4][WCHUNK];

    int blk = blockIdx.x;
    int wc = blk & 7;              // 8 w-chunks
    int bv = blk >> 3;
    int v = bv % VIEWS;
    int b = bv / VIEWS;

    int tid = threadIdx.x;
    int lane = tid & 63;
    int g = tid >> 6;              // wave id 0..3 = h phase
    int w = wc * WCHUNK + lane;

    double ang = -3.14159265358979323846 * (double)(v + 1) / (double)VIEWS
                 - 3.14159265358979323846;
    float c = (float)cos(ang);
    float s = (float)sin(ang);

    const float* __restrict__ img = x + (size_t)b * IMGSZ * IMGSZ;

    // ix = cxw - s*hh ; iy = sxw + c*hh ; hh = h - 255.5
    float xw = (float)w + 0.5f - 256.0f;
    float cxw = fmaf(c, xw, 255.5f);
    float sxw = fmaf(s, xw, 255.5f);

    // Per-thread valid-h interval (identical to baseline).
    float lo = -1e30f, hi = 1e30f;
    {
        float coef = -s, base = cxw;
        if (fabsf(coef) > 1e-6f) {
            float a = (-1.0f - base) / coef;
            float bq = (512.0f - base) / coef;
            lo = fmaxf(lo, fminf(a, bq));
            hi = fminf(hi, fmaxf(a, bq));
        } else if (!(base > -1.0f && base < 512.0f)) {
            lo = 1e30f; hi = -1e30f;
        }
    }
    {
        float coef = c, base = sxw;
        if (fabsf(coef) > 1e-6f) {
            float a = (-1.0f - base) / coef;
            float bq = (512.0f - base) / coef;
            lo = fmaxf(lo, fminf(a, bq));
            hi = fminf(hi, fmaxf(a, bq));
        } else if (!(base > -1.0f && base < 512.0f)) {
            lo = 1e30f; hi = -1e30f;
        }
    }
    float h0f = fminf(fmaxf(floorf(lo + 255.5f) - 1.0f, 0.0f), 512.0f);
    float h1f = fminf(fmaxf(ceilf(hi + 255.5f) + 1.0f, -1.0f), 511.0f);
    int h0 = (int)h0f;
    int h1 = (int)h1f;

    // Block-uniform h range: each wave holds all 64 w values -> wave reduce.
    int bh0 = h0, bh1 = h1;
    #pragma unroll
    for (int m = 1; m < 64; m <<= 1) {
        bh0 = min(bh0, __shfl_xor(bh0, m, 64));
        bh1 = max(bh1, __shfl_xor(bh1, m, 64));
    }
    // (identical in every wave since every wave spans the same w set)

    // Block corner constants for bounding boxes.
    float xa = (float)(wc * WCHUNK) + 0.5f - 256.0f;
    float xb = xa + 63.0f;

    float acc = 0.0f;

    for (int hc = bh0; hc <= bh1; hc += KH) {
        int hend = min(hc + KH - 1, bh1);

        // Bounding box of sample coords over w in [w0,w0+63], h in [hc,hend].
        float ha = (float)hc - 255.5f;
        float hb = (float)hend - 255.5f;
        float ix00 = c * xa - s * ha, ix01 = c * xa - s * hb;
        float ix10 = c * xb - s * ha, ix11 = c * xb - s * hb;
        float iy00 = s * xa + c * ha, iy01 = s * xa + c * hb;
        float iy10 = s * xb + c * ha, iy11 = s * xb + c * hb;
        float ixmn = fminf(fminf(ix00, ix01), fminf(ix10, ix11)) + 255.5f;
        float ixmx = fmaxf(fmaxf(ix00, ix01), fmaxf(ix10, ix11)) + 255.5f;
        float iymn = fminf(fminf(iy00, iy01), fminf(iy10, iy11)) + 255.5f;
        float iymx = fmaxf(fmaxf(iy00, iy01), fmaxf(iy10, iy11)) + 255.5f;
        int x_lo = (int)floorf(ixmn) - 1;          // -1 margin for fp slop
        int y_lo = (int)floorf(iymn) - 1;
        int NX = min((int)floorf(ixmx) + 2 - x_lo + 1, MAXB);
        int NY = min((int)floorf(iymx) + 2 - y_lo + 1, MAXB);

        __syncthreads();   // previous chunk's gathers done before overwrite

        // Stage box -> LDS. Clamped (finite) values outside image; weights
        // mask them to zero in the gather.
        {
            int total = NY * NX;
            int i = tid;
            int ry = i / NX;
            int rx = i - ry * NX;
            while (i < total) {
                int gy = min(max(y_lo + ry, 0), IMGSZ - 1);
                int gx = min(max(x_lo + rx, 0), IMGSZ - 1);
                tile[ry * PITCH + rx] = img[gy * IMGSZ + gx];
                i += 256;
                rx += 256;
                while (rx >= NX) { rx -= NX; ++ry; }
            }
        }
        __syncthreads();

        // Gather from LDS: this wave handles h = hc+g, hc+g+4, ...
        for (int h = hc + g; h <= hend; h += 4) {
            float hh = (float)h - 255.5f;
            float ix = fmaf(-s, hh, cxw);
            float iy = fmaf(c, hh, sxw);
            float fx = floorf(ix);
            float fy = floorf(iy);
            int x0 = (int)fx;
            int y0 = (int)fy;
            float wx1 = ix - fx;
            float wy1 = iy - fy;
            float wx0 = 1.0f - wx1;
            float wy0 = 1.0f - wy1;
            bool vx0 = (unsigned)x0 < (unsigned)IMGSZ;
            bool vx1 = (unsigned)(x0 + 1) < (unsigned)IMGSZ;
            bool vy0 = (unsigned)y0 < (unsigned)IMGSZ;
            bool vy1 = (unsigned)(y0 + 1) < (unsigned)IMGSZ;
            float w00 = (vx0 && vy0) ? wx0 * wy0 : 0.0f;
            float w01 = (vx1 && vy0) ? wx1 * wy0 : 0.0f;
            float w10 = (vx0 && vy1) ? wx0 * wy1 : 0.0f;
            float w11 = (vx1 && vy1) ? wx1 * wy1 : 0.0f;
            int lx = min(max(x0 - x_lo, 0), NX - 2);
            int ly = min(max(y0 - y_lo, 0), NY - 2);
            const float* p = tile + ly * PITCH + lx;
            acc = fmaf(p[0], w00, acc);
            acc = fmaf(p[1], w01, acc);
            acc = fmaf(p[PITCH], w10, acc);
            acc = fmaf(p[PITCH + 1], w11, acc);
        }
    }

    // Combine the 4 h-phase partials per w.
    part[g][lane] = acc;
    __syncthreads();
    if (g == 0) {
        float r = part[0][lane] + part[1][lane] + part[2][lane] + part[3][lane];
        out[((size_t)(b * IMGSZ + w)) * VIEWS + v] = r * 0.5f;
    }
}

extern "C" void kernel_launch(void* const* d_in, const int* in_sizes, int n_in,
                              void* d_out, int out_size, void* d_ws, size_t ws_size,
                              hipStream_t stream) {
    const float* x = (const float*)d_in[0];
    float* out = (float*)d_out;
    int nblocks = BATCH * VIEWS * (IMGSZ / WCHUNK);   // 5760
    fp_kernel<<<nblocks, 256, 0, stream>>>(x, out);
}

// Round 4
// 349.456 us; speedup vs baseline: 2.1622x; 1.6111x over previous
//
#include <hip/hip_runtime.h>

constexpr int VIEWS = 360;
constexpr int IMGSZ = 512;
constexpr int BATCH = 2;
constexpr int WCHUNK = 64;   // w per block
constexpr int KH = 64;       // h per LDS chunk
constexpr int MAXB = 95;     // max bounding-box dim: 63*sqrt(2)+4 < 95
constexpr int PITCH = 97;    // odd pitch -> benign LDS bank pattern

// Block = (b, v, wc): 64 detector bins, 4 waves split the h-sum stride-4.
// Per 64-h chunk: stage the rotated square's bounding box into LDS with
// ZEROS outside the image (so out-of-image taps contribute 0 with no
// per-tap masking), then bilinear-gather from LDS with a maskless,
// clampless 3-lerp body. Box margins guarantee in-tile taps for every
// (w,h) in the chunk rectangle, valid or not.
__global__ __launch_bounds__(256) void fp_kernel(const float* __restrict__ x,
                                                 float* __restrict__ out) {
    __shared__ float tile[MAXB * PITCH];
    __shared__ float part[4][WCHUNK];

    int blk = blockIdx.x;
    int wc = blk & 7;              // 8 w-chunks
    int bv = blk >> 3;
    int v = bv % VIEWS;
    int b = bv / VIEWS;

    int tid = threadIdx.x;
    int lane = tid & 63;
    int g = tid >> 6;              // wave id 0..3 = h phase
    int w = wc * WCHUNK + lane;

    double ang = -3.14159265358979323846 * (double)(v + 1) / (double)VIEWS
                 - 3.14159265358979323846;
    float c = (float)cos(ang);
    float s = (float)sin(ang);

    const float* __restrict__ img = x + (size_t)b * IMGSZ * IMGSZ;

    // ix = cxw - s*hh ; iy = sxw + c*hh ; hh = h - 255.5
    float xw = (float)w + 0.5f - 256.0f;
    float cxw = fmaf(c, xw, 255.5f);
    float sxw = fmaf(s, xw, 255.5f);

    // Per-thread valid-h interval (identical to validated baseline).
    float lo = -1e30f, hi = 1e30f;
    {
        float coef = -s, base = cxw;
        if (fabsf(coef) > 1e-6f) {
            float a = (-1.0f - base) / coef;
            float bq = (512.0f - base) / coef;
            lo = fmaxf(lo, fminf(a, bq));
            hi = fminf(hi, fmaxf(a, bq));
        } else if (!(base > -1.0f && base < 512.0f)) {
            lo = 1e30f; hi = -1e30f;
        }
    }
    {
        float coef = c, base = sxw;
        if (fabsf(coef) > 1e-6f) {
            float a = (-1.0f - base) / coef;
            float bq = (512.0f - base) / coef;
            lo = fmaxf(lo, fminf(a, bq));
            hi = fminf(hi, fmaxf(a, bq));
        } else if (!(base > -1.0f && base < 512.0f)) {
            lo = 1e30f; hi = -1e30f;
        }
    }
    float h0f = fminf(fmaxf(floorf(lo + 255.5f) - 1.0f, 0.0f), 512.0f);
    float h1f = fminf(fmaxf(ceilf(hi + 255.5f) + 1.0f, -1.0f), 511.0f);
    int h0 = (int)h0f;
    int h1 = (int)h1f;

    // Block-uniform h range (same in every wave: all waves span same w set).
    int bh0 = h0, bh1 = h1;
    #pragma unroll
    for (int m = 1; m < 64; m <<= 1) {
        bh0 = min(bh0, __shfl_xor(bh0, m, 64));
        bh1 = max(bh1, __shfl_xor(bh1, m, 64));
    }

    float xa = (float)(wc * WCHUNK) + 0.5f - 256.0f;
    float xb = xa + 63.0f;

    float acc = 0.0f;
    float step4x = -4.0f * s;   // per-iteration coord increment (h stride 4)
    float step4y = 4.0f * c;

    for (int hc = bh0; hc <= bh1; hc += KH) {
        int hend = min(hc + KH - 1, bh1);

        // Bounding box of sample coords over the chunk rectangle.
        float ha = (float)hc - 255.5f;
        float hb = (float)hend - 255.5f;
        float ix00 = c * xa - s * ha, ix01 = c * xa - s * hb;
        float ix10 = c * xb - s * ha, ix11 = c * xb - s * hb;
        float iy00 = s * xa + c * ha, iy01 = s * xa + c * hb;
        float iy10 = s * xb + c * ha, iy11 = s * xb + c * hb;
        float ixmn = fminf(fminf(ix00, ix01), fminf(ix10, ix11)) + 255.5f;
        float iymn = fminf(fminf(iy00, iy01), fminf(iy10, iy11)) + 255.5f;
        float iymx = fmaxf(fmaxf(iy00, iy01), fmaxf(iy10, iy11)) + 255.5f;
        int x_lo = (int)floorf(ixmn) - 1;          // >=1px fp-slop margin
        int y_lo = (int)floorf(iymn) - 1;
        int NY = min((int)floorf(iymx) + 3 - y_lo, MAXB);

        __syncthreads();   // previous chunk's gathers done before overwrite

        // Stage fixed-width 95 x NY box -> LDS, zeros outside the image.
        // Compile-time divisor 95 -> magic-multiply, no carry loop.
        {
            int total = NY * MAXB;
            for (int i = tid; i < total; i += 256) {
                int ry = i / MAXB;
                int rx = i - ry * MAXB;
                int gx = x_lo + rx;
                int gy = y_lo + ry;
                bool ok = ((unsigned)gx < (unsigned)IMGSZ) &
                          ((unsigned)gy < (unsigned)IMGSZ);
                int idx = ok ? (gy * IMGSZ + gx) : 0;
                float val = img[idx];
                tile[ry * PITCH + rx] = ok ? val : 0.0f;
            }
        }
        __syncthreads();

        // Maskless clampless gather: this wave handles h = hc+g, +4, ...
        float hh0 = (float)(hc + g) - 255.5f;
        float ixr = fmaf(-s, hh0, cxw) - (float)x_lo;
        float iyr = fmaf(c, hh0, sxw) - (float)y_lo;
        #pragma unroll 4
        for (int h = hc + g; h <= hend; h += 4) {
            float fx = floorf(ixr);
            float fy = floorf(iyr);
            int lx = (int)fx;
            int ly = (int)fy;
            float wx1 = ixr - fx;
            float wy1 = iyr - fy;
            const float* p = tile + (ly * PITCH + lx);
            float t00 = p[0];
            float t01 = p[1];
            float t10 = p[PITCH];
            float t11 = p[PITCH + 1];
            float l0 = fmaf(wx1, t01 - t00, t00);
            float l1 = fmaf(wx1, t11 - t10, t10);
            acc = fmaf(wy1, l1 - l0, acc + l0);
            ixr += step4x;
            iyr += step4y;
        }
    }

    // Combine the 4 h-phase partials per w.
    part[g][lane] = acc;
    __syncthreads();
    if (g == 0) {
        float r = part[0][lane] + part[1][lane] + part[2][lane] + part[3][lane];
        out[((size_t)(b * IMGSZ + w)) * VIEWS + v] = r * 0.5f;
    }
}

extern "C" void kernel_launch(void* const* d_in, const int* in_sizes, int n_in,
                              void* d_out, int out_size, void* d_ws, size_t ws_size,
                              hipStream_t stream) {
    const float* x = (const float*)d_in[0];
    float* out = (float*)d_out;
    int nblocks = BATCH * VIEWS * (IMGSZ / WCHUNK);   // 5760
    fp_kernel<<<nblocks, 256, 0, stream>>>(x, out);
}

// Round 5
// 228.182 us; speedup vs baseline: 3.3114x; 1.5315x over previous
//
#include <hip/hip_runtime.h>

constexpr int VIEWS = 360;
constexpr int IMGSZ = 512;
constexpr int BATCH = 2;
constexpr int WCHUNK = 64;   // w per block
constexpr int KH = 64;       // h per LDS chunk
constexpr int NXF4 = 25;     // staged box width in float4 (100 floats)
constexpr int PITCH = 100;   // LDS row pitch (floats)
constexpr int MAXNY = 94;    // max staged rows: 63*(|s|+|c|)+4 <= 93.2
constexpr int PW = 712;      // padded image width  (mult of 4, 96+512+104 slack)
constexpr int PH = 704;      // padded image height (96+512+96)
constexpr int PAD = 96;

// ---------- pad kernel: zero-padded copy of both images into d_ws ----------
__global__ __launch_bounds__(256) void pad_kernel(const float* __restrict__ x,
                                                  float* __restrict__ pad) {
    constexpr int rowf4 = PW / 4;            // 178
    constexpr int perimg = PH * rowf4;       // 125312 float4
    int idx = blockIdx.x * 256 + threadIdx.x;
    if (idx >= BATCH * perimg) return;
    int b = idx / perimg;
    int r = idx - b * perimg;
    int py = r / rowf4;
    int px4 = r - py * rowf4;
    int gx = px4 * 4 - PAD;                  // multiple of 4 -> float4 all-in/all-out
    int gy = py - PAD;
    float4 v = make_float4(0.f, 0.f, 0.f, 0.f);
    if ((unsigned)gy < (unsigned)IMGSZ && (unsigned)gx < (unsigned)IMGSZ)
        v = *(const float4*)(x + ((size_t)b * IMGSZ + gy) * IMGSZ + gx);
    *(float4*)(pad + (size_t)idx * 4) = v;
}

// ---------- main kernel: maskless float4 staging from padded image ----------
__global__ __launch_bounds__(256) void fp_kernel(const float* __restrict__ pad,
                                                 float* __restrict__ out) {
    __shared__ __align__(16) float tile[NXF4 * 4 * 1024 / 10];  // placeholder sized below
    // (real size: 2560 float4 = 10240 floats = 40960 B; see static_assert)
    static_assert(sizeof(tile) >= 0, "");
    // -- actual array --
    // NOTE: expression above must be exactly 10240 floats:
    //   10*256 float4 slots (nit<=10) * 4 floats
    // 25*4*1024/10 = 10240  ✓

    int blk = blockIdx.x;
    int wc = blk & 7;
    int bv = blk >> 3;
    int v = bv % VIEWS;
    int b = bv / VIEWS;

    int tid = threadIdx.x;
    int lane = tid & 63;
    int g = tid >> 6;
    int w = wc * WCHUNK + lane;

    double ang = -3.14159265358979323846 * (double)(v + 1) / (double)VIEWS
                 - 3.14159265358979323846;
    float c = (float)cos(ang);
    float s = (float)sin(ang);

    const float* __restrict__ pimg = pad + (size_t)b * PH * PW;

    float xw = (float)w + 0.5f - 256.0f;
    float cxw = fmaf(c, xw, 255.5f);
    float sxw = fmaf(s, xw, 255.5f);

    // Per-thread valid-h interval (identical to validated rounds 2-4).
    float lo = -1e30f, hi = 1e30f;
    {
        float coef = -s, base = cxw;
        if (fabsf(coef) > 1e-6f) {
            float a = (-1.0f - base) / coef;
            float bq = (512.0f - base) / coef;
            lo = fmaxf(lo, fminf(a, bq));
            hi = fminf(hi, fmaxf(a, bq));
        } else if (!(base > -1.0f && base < 512.0f)) {
            lo = 1e30f; hi = -1e30f;
        }
    }
    {
        float coef = c, base = sxw;
        if (fabsf(coef) > 1e-6f) {
            float a = (-1.0f - base) / coef;
            float bq = (512.0f - base) / coef;
            lo = fmaxf(lo, fminf(a, bq));
            hi = fminf(hi, fmaxf(a, bq));
        } else if (!(base > -1.0f && base < 512.0f)) {
            lo = 1e30f; hi = -1e30f;
        }
    }
    float h0f = fminf(fmaxf(floorf(lo + 255.5f) - 1.0f, 0.0f), 512.0f);
    float h1f = fminf(fmaxf(ceilf(hi + 255.5f) + 1.0f, -1.0f), 511.0f);
    int h0 = (int)h0f;
    int h1 = (int)h1f;

    int bh0 = h0, bh1 = h1;
    #pragma unroll
    for (int m = 1; m < 64; m <<= 1) {
        bh0 = min(bh0, __shfl_xor(bh0, m, 64));
        bh1 = max(bh1, __shfl_xor(bh1, m, 64));
    }

    float xa = (float)(wc * WCHUNK) + 0.5f - 256.0f;
    float xb = xa + 63.0f;

    float acc = 0.0f;
    float step4x = -4.0f * s;
    float step4y = 4.0f * c;

    for (int hc = bh0; hc <= bh1; hc += KH) {
        int hend = min(hc + KH - 1, bh1);

        float ha = (float)hc - 255.5f;
        float hb = (float)hend - 255.5f;
        float ix00 = c * xa - s * ha, ix01 = c * xa - s * hb;
        float ix10 = c * xb - s * ha, ix11 = c * xb - s * hb;
        float iy00 = s * xa + c * ha, iy01 = s * xa + c * hb;
        float iy10 = s * xb + c * ha, iy11 = s * xb + c * hb;
        float ixmn = fminf(fminf(ix00, ix01), fminf(ix10, ix11)) + 255.5f;
        float iymn = fminf(fminf(iy00, iy01), fminf(iy10, iy11)) + 255.5f;
        float iymx = fmaxf(fmaxf(iy00, iy01), fmaxf(iy10, iy11)) + 255.5f;
        int x_lo = (int)floorf(ixmn) - 1;
        int x_lo4 = x_lo & ~3;              // float4-align (floors negatives)
        int y_lo = (int)floorf(iymn) - 1;
        int NY = min((int)floorf(iymx) + 3 - y_lo, MAXNY);
        int total4 = NY * NXF4;
        int nit = (total4 + 255) >> 8;      // <= 10

        __syncthreads();

        // Maskless staging: padded image guarantees in-bounds, zero outside.
        // LDS layout: float4 slot i at byte 16*i -> rows of 25 float4 (PITCH=100).
        {
            const float* pb = pimg + (y_lo + PAD) * PW + (x_lo4 + PAD);
            for (int k = 0; k < nit; ++k) {
                int i = (k << 8) + tid;
                int ic = min(i, total4 - 1);          // clamp trailing lanes
                int ry = ic / NXF4;                   // magic-mul
                float4 val = *(const float4*)(pb + 4 * ic + (PW - 4 * NXF4) * ry);
                *(float4*)&tile[i << 2] = val;        // contiguous, conflict-free
            }
        }
        __syncthreads();

        // Maskless clampless gather; wave g handles h = hc+g, +4, ...
        float hh0 = (float)(hc + g) - 255.5f;
        float ixr = fmaf(-s, hh0, cxw) - (float)x_lo4;
        float iyr = fmaf(c, hh0, sxw) - (float)y_lo;
        #pragma unroll 4
        for (int h = hc + g; h <= hend; h += 4) {
            float fx = floorf(ixr);
            float fy = floorf(iyr);
            int lx = (int)fx;
            int ly = (int)fy;
            float wx1 = ixr - fx;
            float wy1 = iyr - fy;
            const float* p = tile + (ly * PITCH + lx);
            float t00 = p[0];
            float t01 = p[1];
            float t10 = p[PITCH];
            float t11 = p[PITCH + 1];
            float l0 = fmaf(wx1, t01 - t00, t00);
            float l1 = fmaf(wx1, t11 - t10, t10);
            acc = fmaf(wy1, l1 - l0, acc + l0);
            ixr += step4x;
            iyr += step4y;
        }
    }

    // Reduce the 4 h-phase partials, reusing the tile (no extra LDS).
    __syncthreads();
    tile[(g << 6) + lane] = acc;
    __syncthreads();
    if (g == 0) {
        float r = tile[lane] + tile[64 + lane] + tile[128 + lane] + tile[192 + lane];
        out[((size_t)(b * IMGSZ + w)) * VIEWS + v] = r * 0.5f;
    }
}

extern "C" void kernel_launch(void* const* d_in, const int* in_sizes, int n_in,
                              void* d_out, int out_size, void* d_ws, size_t ws_size,
                              hipStream_t stream) {
    const float* x = (const float*)d_in[0];
    float* out = (float*)d_out;
    float* pad = (float*)d_ws;    // needs BATCH*PH*PW*4 = 4,009,984 bytes

    constexpr int padTotal = BATCH * PH * (PW / 4);   // 250624 float4
    pad_kernel<<<(padTotal + 255) / 256, 256, 0, stream>>>(x, pad);

    int nblocks = BATCH * VIEWS * (IMGSZ / WCHUNK);   // 5760
    fp_kernel<<<nblocks, 256, 0, stream>>>(pad, out);
}